// Round 11
// baseline (160.714 us; speedup 1.0000x reference)
//
#include <hip/hip_runtime.h>
#include <stdint.h>

#define NB 32
#define NP 32768
#define NO 32
#define THRESH 0.35f
#define NT1 64          // kern1 x-tiles (512 priors each)
#define HCOL 33         // kern3 histogram columns (conflict immunity — R4 lesson)

typedef unsigned long long u64;
typedef unsigned int u32;

// fast IoU from prior corners + truth corners. kern1's additions and kern3's
// delta-subtractions must cancel bit-exactly, so BOTH use this helper.
__device__ __forceinline__ float iou_corners(float px1, float py1, float px2, float py2, float ab,
                                             float tx1, float ty1, float tx2, float ty2, float aa)
{
#pragma clang fp contract(off)
    float iw = fminf(tx2, px2) - fmaxf(tx1, px1);
    float ih = fminf(ty2, py2) - fmaxf(ty1, py1);
    iw = fmaxf(iw, 0.f); ih = fmaxf(ih, 0.f);
    float inter = iw * ih;
    return __fdividef(inter, aa + ab - inter);
}

// smooth-L1 of (loc - encode(truth, prior)), summed over 4 coords
__device__ __forceinline__ float smooth_l1_sum(float4 ld, float4 pr, float4 tt)
{
#pragma clang fp contract(off)
    float g0 = __fdividef((tt.x + tt.z) * 0.5f - pr.x, 0.1f * pr.z);
    float g1 = __fdividef((tt.y + tt.w) * 0.5f - pr.y, 0.1f * pr.w);
    float g2 = __logf(__fdividef(tt.z - tt.x, pr.z)) * 5.0f;
    float g3 = __logf(__fdividef(tt.w - tt.y, pr.w)) * 5.0f;
    float d0 = ld.x - g0, d1 = ld.y - g1, d2 = ld.z - g2, d3 = ld.w - g3;
    float a0 = fabsf(d0), a1 = fabsf(d1), a2 = fabsf(d2), a3 = fabsf(d3);
    return (a0 < 1.f ? 0.5f * d0 * d0 : a0 - 0.5f)
         + (a1 < 1.f ? 0.5f * d1 * d1 : a1 - 0.5f)
         + (a2 < 1.f ? 0.5f * d2 * d2 : a2 - 0.5f)
         + (a3 < 1.f ? 0.5f * d3 * d3 : a3 - 0.5f);
}

__device__ __forceinline__ float lse2(float c0, float c1)
{
#pragma clang fp contract(off)
    float mm = fmaxf(c0, c1), mn = fminf(c0, c1);
    return mm + __logf(1.f + __expf(mn - mm));
}

// ---------------- K1: IoU + per-prior best + PRE-FIX losses + mine, all fused ----------
// grid (64 tiles, 32 batches) x 256 threads; each thread owns 2 CONSECUTIVE priors.
// 2048 blocks -> 8 blocks/CU -> 32 waves/CU (max occupancy; VGPR=32 permits it).
// NOTE: o is STAGGERED per lane (o = (it + lane%32) & 31). Load-bearing: spreads
// keys[o] reads/atomics over 32 LDS addresses (2 lanes/addr = conflict-free).
// Wave-uniform o funnels 64-lane same-address DS atomics -> DS-pipe serialization
// (measured R5: kern1 44->95 us with VALUBusy unchanged).
// R12: (a) loc load + smooth_l1 PREDICATED on pos; (b) ta[] inlined.
// R17 INSTRUMENTATION: kern1 launched TWICE (idempotent — all outputs are pure
// functions of inputs; accumulator zero-init is constant; kern3 runs after both).
// wall_delta vs R16 (126.96) == kern1's warm duration. Pre-committed read:
//   wall 165-175 -> kern1~43 (hyp A: kern1 3-4x above VALU floor, attack it)
//   wall 135-142 -> kern1~10 (hyp B: kern3 dominates controllable budget)
__global__ __launch_bounds__(256) void kern1(
        const float* __restrict__ loc, const float* __restrict__ conf,
        const float* __restrict__ priors, const float* __restrict__ targets,
        float* __restrict__ mine, u64* __restrict__ bpk_part,
        float* __restrict__ part_sl1, float* __restrict__ part_cep, int* __restrict__ part_np,
        float* __restrict__ sl_tot, float* __restrict__ c_tot,
        int* __restrict__ np_tot, int* __restrict__ done_cnt)
{
#pragma clang fp contract(off)
    __shared__ __align__(16) float4 tbc[NO];   // truth corners
    __shared__ float tlab[NO];
    __shared__ u64 keys[NO];
    __shared__ float rs0[4], rs1[4];
    __shared__ int rc[4];
    const int b = blockIdx.y, x = blockIdx.x, tid = threadIdx.x;
    if (b == 0 && x == 0 && tid == 0) {        // init accumulators for kern3 (runs after us)
        *sl_tot = 0.f; *c_tot = 0.f; *np_tot = 0; *done_cnt = 0;
    }
    if (tid < NO * 5) {
        int o = tid / 5, c = tid % 5;
        float v = targets[b * NO * 5 + tid];
        if (c < 4) ((float*)&tbc[o])[c] = v; else tlab[o] = v;
    }
    if (tid < NO) keys[tid] = 0ull;
    __syncthreads();

    const int p0 = x * 512 + tid * 2;
    float4 pr[2];
    float px1[2], py1[2], px2[2], py2[2], ab[2];
#pragma unroll
    for (int j = 0; j < 2; ++j) {
        pr[j] = ((const float4*)priors)[p0 + j];
        px1[j] = pr[j].x - pr[j].z * 0.5f;
        py1[j] = pr[j].y - pr[j].w * 0.5f;
        px2[j] = pr[j].x + pr[j].z * 0.5f;
        py2[j] = pr[j].y + pr[j].w * 0.5f;
        ab[j]  = pr[j].z * pr[j].w;
    }
    // per-prior best truth as packed u64: (iou_bits << 6) | (63 - o)
    // max => largest iou, tie => smallest o (reference first-max argmax)
    u64 bk[2] = {0ull, 0ull};
    const int lane_o = tid & 31;   // stagger (see note above)
    for (int it = 0; it < NO; ++it) {
        const int o = (it + lane_o) & 31;
        float4 tt = tbc[o];
        float aa = (tt.z - tt.x) * (tt.w - tt.y);   // inline area (bit-identical to old ta[o])
        float iou2[2];
#pragma unroll
        for (int j = 0; j < 2; ++j) {
            float iou = iou_corners(px1[j], py1[j], px2[j], py2[j], ab[j],
                                    tt.x, tt.y, tt.z, tt.w, aa);
            iou2[j] = iou;
            u64 ko = ((u64)__float_as_uint(iou) << 6) | (u64)(63 - o);
            bk[j] = bk[j] > ko ? bk[j] : ko;
        }
        // per-truth best prior: cheap value-only filter, rare full path
        float vm = fmaxf(iou2[0], iou2[1]);
        u64 cur = keys[o];
        if (__float_as_uint(vm) > (u32)(cur >> 32)) {
            float bi = iou2[1]; int bp = p0 + 1;
            if (iou2[0] >= bi) { bi = iou2[0]; bp = p0; }
            atomicMax(&keys[o], ((u64)__float_as_uint(bi) << 32) | (u64)(~(u32)bp));
        }
    }

    // ---- pre-fix losses straight from registers ----
    const size_t gbase = (size_t)b * NP + p0;
    float4 cf = ((const float4*)conf)[gbase >> 1];
    float c0[2] = {cf.x, cf.z};
    float c1[2] = {cf.y, cf.w};
    float2 mout;
    float s_sl1 = 0.f, s_cep = 0.f;
    int np = 0;
#pragma unroll
    for (int j = 0; j < 2; ++j) {
        u32 vb = (u32)(bk[j] >> 6);
        float bv = __uint_as_float(vb);
        int o = 63 - (int)(bk[j] & 63);
        int cfv = (bv < THRESH) ? 0 : ((int)tlab[o] + 1);
        bool pos = cfv > 0;
        float ce = lse2(c0[j], c1[j]) - ((cfv == 0) ? c0[j] : c1[j]);
        if (pos) {                                  // exec-masked: no loc fetch, no sl1
            float4 ld = ((const float4*)loc)[gbase + j];   // math for ~99% of priors
            s_sl1 += smooth_l1_sum(ld, pr[j], tbc[o]);
            s_cep += ce;
            np++;
        }
        ((float*)&mout)[j] = pos ? 0.f : ce;
    }
    ((float2*)mine)[gbase >> 1] = mout;

#pragma unroll
    for (int m = 32; m; m >>= 1) {
        s_sl1 += __shfl_xor(s_sl1, m, 64);
        s_cep += __shfl_xor(s_cep, m, 64);
        np    += __shfl_xor(np, m, 64);
    }
    int lane = tid & 63, w = tid >> 6;
    if (lane == 0) { rs0[w] = s_sl1; rs1[w] = s_cep; rc[w] = np; }
    __syncthreads();
    if (tid == 0) {
        float t0 = 0.f, t1 = 0.f; int t2 = 0;
        for (int i = 0; i < 4; ++i) { t0 += rs0[i]; t1 += rs1[i]; t2 += rc[i]; }
        part_sl1[b * NT1 + x] = t0;
        part_cep[b * NT1 + x] = t1;
        part_np [b * NT1 + x] = t2;
    }
    if (tid < NO) bpk_part[(b * NT1 + x) * 32 + tid] = keys[tid];  // after the sync above
}

// ---------------- K3: wave-specialized fix + column radix-select top-k + finalize ------
// R11: kern3 is ONE block/batch on ONE CU -> everything serializes per-CU. All 16
// waves issue v loads FIRST (per-wave vmcnt drain at the barrier), then WAVE 15
// ALONE does targets->tbc, parallel bpk resolve (64 lanes x 32 loads all in
// flight), and the fix phase -- all within-wave, hidden UNDER the other waves'
// load drain. Fix precedes pass-0, so the histogram is built on post-fix values
// directly. Sum trees bit-identical to verified versions. UNCHANGED this round.
__global__ __launch_bounds__(1024) void kern3(
        const float* __restrict__ loc, const float* __restrict__ conf,
        const float* __restrict__ priors, const float* __restrict__ targets,
        const u64* __restrict__ bpk_part, const float* __restrict__ mine,
        const float* __restrict__ part_sl1, const float* __restrict__ part_cep,
        const int* __restrict__ part_np,
        float* __restrict__ sl_tot, float* __restrict__ c_tot,
        int* __restrict__ np_tot, int* __restrict__ done_cnt,
        float* __restrict__ out)
{
#pragma clang fp contract(off)
    const int b = blockIdx.x, tid = threadIdx.x;
    const int wave = tid >> 6, lane = tid & 63;
    const int cl = lane & 31;                   // histogram column
    __shared__ __align__(16) float4 tbc[NO];
    __shared__ float tlab[NO], tas[NO];
    __shared__ u32 pp_s[NO];
    __shared__ u32 flags[1024];                 // 32768-bit mask of forced priors
    __shared__ int hA[256 * HCOL], hB[256 * HCOL];  // 66 KB ping-pong column hists
    __shared__ float dslA[NO], dceA[NO];
    __shared__ int dnpA[NO];
    __shared__ int wtot[4];
    __shared__ float rs[16];
    __shared__ int rc2[16];
    __shared__ float sh_sl1, sh_cep;
    __shared__ int sh_np, sh_k, sh_kk;
    __shared__ u32 sh_prefix;

    // ---- all waves: issue the mine loads FIRST (each wave drains only its own) ----
    const float* mb = mine + (size_t)b * NP;
    float v[32];
#pragma unroll
    for (int q = 0; q < 8; ++q) {
        float4 t4 = ((const float4*)mb)[q * 1024 + tid];
        v[4 * q] = t4.x; v[4 * q + 1] = t4.y; v[4 * q + 2] = t4.z; v[4 * q + 3] = t4.w;
    }

    if (wave < 15) {
        // clears only; these waves then sit at the barrier while their loads drain
        for (int i = tid; i < 256 * HCOL; i += 960) { hA[i] = 0; hB[i] = 0; }
    } else {
        // ---- wave 15: serial front-half, overlapped under the other waves' drain ----
        // flags clear (wave-15-owned: no race with its own later atomicOr)
        for (int i = lane; i < 1024; i += 64) flags[i] = 0u;
        // targets: 160 floats via 3 loads/lane
        float tv0 = targets[b * NO * 5 + lane];
        float tv1 = targets[b * NO * 5 + 64 + lane];
        float tv2 = (lane < 32) ? targets[b * NO * 5 + 128 + lane] : 0.f;
        // bpk resolve: lane = o + 32*h handles xx in [32h, 32h+32) -> all loads in flight
        const int ro = lane & 31, rh = lane >> 5;
        const u64* bp = bpk_part + ((size_t)(b * NT1 + rh * 32)) * 32 + ro;
        u64 key = 0ull;
#pragma unroll
        for (int j = 0; j < 32; ++j) {
            u64 t2 = bp[(size_t)j * 32];
            key = t2 > key ? t2 : key;
        }
        // scatter targets to LDS (same-wave lgkmcnt ordering; no block barrier needed)
        {
            int e = lane;       int o = e / 5, c = e % 5;
            if (c < 4) ((float*)&tbc[o])[c] = tv0; else tlab[o] = tv0;
            e = lane + 64;      o = e / 5;  c = e % 5;
            if (c < 4) ((float*)&tbc[o])[c] = tv1; else tlab[o] = tv1;
            if (lane < 32) {
                e = lane + 128; o = e / 5;  c = e % 5;
                if (c < 4) ((float*)&tbc[o])[c] = tv2; else tlab[o] = tv2;
            }
        }
        if (lane < NO) {
            float4 t = tbc[lane];
            tas[lane] = (t.z - t.x) * (t.w - t.y);
        }
        // combine resolve halves across the wave (lane o <-> o+32)
        {
            u64 t2 = __shfl_xor(key, 32, 64);
            key = t2 > key ? t2 : key;
        }
        u32 ppv = (key >> 32) ? ~(u32)key : 0u;     // all-zero row => argmax = 0
        if (lane < NO) pp_s[lane] = ppv;
        // ---- fix phase: lane = o, serial IoU loop (old A2 body, verbatim math) ----
        if (lane < NO) {
            const int o = lane;
            const u32 p = ppv;
            float dsl1 = 0.f, dcep = 0.f; int dnp = 0;
            bool last = true;
            for (int o2 = o + 1; o2 < NO; ++o2)
                if (pp_s[o2] == p) { last = false; break; }   // later o overwrites same prior
            if (last) {
                float4 prr = ((const float4*)priors)[p];
                float px1 = prr.x - prr.z * 0.5f, py1 = prr.y - prr.w * 0.5f;
                float px2 = prr.x + prr.z * 0.5f, py2 = prr.y + prr.w * 0.5f;
                float ab = prr.z * prr.w;
                // pre-fix best truth for p (natural order, strict > == first-max)
                float bv = -1.f; int bo_ = 0;
                for (int o2 = 0; o2 < NO; ++o2) {
                    float4 t2 = tbc[o2];
                    float i2 = iou_corners(px1, py1, px2, py2, ab, t2.x, t2.y, t2.z, t2.w, tas[o2]);
                    if (i2 > bv) { bv = i2; bo_ = o2; }
                }
                int cf_pre = (bv < THRESH) ? 0 : ((int)tlab[bo_] + 1);
                size_t gp = (size_t)b * NP + p;
                float4 ld = ((const float4*)loc)[gp];
                float2 c = ((const float2*)conf)[gp];
                float lse = lse2(c.x, c.y);
                int cf_new = (int)tlab[o] + 1;               // forced positive
                dsl1 = smooth_l1_sum(ld, prr, tbc[o]);
                dcep = lse - ((cf_new == 0) ? c.x : c.y);
                dnp = 1;
                if (cf_pre > 0) {                            // remove pre-fix contribution
                    dsl1 -= smooth_l1_sum(ld, prr, tbc[bo_]);
                    dcep -= lse - ((cf_pre == 0) ? c.x : c.y);
                    dnp = 0;
                }
                atomicOr(&flags[p >> 5], 1u << (p & 31));
            }
            dslA[o] = dsl1; dceA[o] = dcep; dnpA[o] = dnp;
        }
    }
    __syncthreads();   // B1: v in regs, tbc/tas/pp/flags/deltas ready

    // ---- A3: zero forced v in-register, then pass-0 histogram on POST-fix values ----
#pragma unroll
    for (int q = 0; q < 8; ++q) {
        u32 word = flags[q * 128 + (tid >> 3)];
#pragma unroll
        for (int c = 0; c < 4; ++c)
            if ((word >> (((tid & 7) << 2) + c)) & 1u) v[4 * q + c] = 0.f;
    }
#pragma unroll 8
    for (int j = 0; j < 32; ++j)
        atomicAdd(&hA[(__float_as_uint(v[j]) >> 24) * HCOL + cl], 1);
    // batch stats (same order/tree as verified versions -> bit-identical)
    if (tid < NO) {
        float a = part_sl1[b * NT1 + tid] + part_sl1[b * NT1 + 32 + tid] + dslA[tid];
        float d = part_cep[b * NT1 + tid] + part_cep[b * NT1 + 32 + tid] + dceA[tid];
        int   n = part_np [b * NT1 + tid] + part_np [b * NT1 + 32 + tid] + dnpA[tid];
#pragma unroll
        for (int m = 16; m; m >>= 1) {
            a += __shfl_xor(a, m, 32);
            d += __shfl_xor(d, m, 32);
            n += __shfl_xor(n, m, 32);
        }
        if (tid == 0) {
            sh_sl1 = a; sh_cep = d; sh_np = n;
            sh_k = min(7 * n, NP - 1); sh_kk = sh_k; sh_prefix = 0u;
        }
    }
    __syncthreads();   // B2: hist + k ready

    const int k = sh_k;
    float topk = 0.f;
    if (k > 0) {
        for (int pass = 0; pass < 4; ++pass) {
            int* cur = (pass & 1) ? hB : hA;
            if (pass > 0) {
                // sparse survivor atomics into cur; overlap clear of the dead buffer
                const int shift = 24 - 8 * pass;
                const u32 pfx = sh_prefix;
#pragma unroll 8
                for (int j = 0; j < 32; ++j) {
                    u32 kb = __float_as_uint(v[j]);
                    if ((u32)(((u64)kb) >> (shift + 8)) == pfx)   // 64-bit shift: defined at 32
                        atomicAdd(&cur[((kb >> shift) & 255) * HCOL + cl], 1);
                }
                if (pass < 3) {                  // other buffer is dead (its scan done);
                    int* other = (pass & 1) ? hA : hB;   // it is cur two passes later
                    for (int i = tid; i < 256 * HCOL; i += 1024) other[i] = 0;
                }
                __syncthreads();
            }
            // merged reduce+scan: thread==bin sums 33 cols + in-wave suffix
            int tot = 0, suf = 0;
            if (tid < 256) {
                const int hb = tid * HCOL;
#pragma unroll
                for (int i = 0; i < HCOL; ++i) tot += cur[hb + i];   // stride 33: no conflicts
                suf = tot;
#pragma unroll
                for (int off = 1; off < 64; off <<= 1) {
                    int u = __shfl_down(suf, off, 64);
                    if (lane + off < 64) suf += u;   // inclusive suffix over higher lanes
                }
                if (lane == 0) wtot[wave] = suf;
            }
            __syncthreads();
            // boundary: unique bin with excl < kk <= excl+tot (suffix order = descending)
            if (tid < 256) {
                int excl = suf - tot;
                for (int w2 = wave + 1; w2 < 4; ++w2) excl += wtot[w2];
                int kk = sh_kk;
                if (excl < kk && kk <= excl + tot) {
                    sh_prefix = (sh_prefix << 8) | (u32)tid;
                    sh_kk = kk - excl;
                }
            }
            __syncthreads();
        }
        // ---- F: sum of strictly-greater + tie fill (identical to verified versions) ----
        const u32 T = sh_prefix;                // exact k-th largest key
        const float tval = __uint_as_float(T);
        float ssum = 0.f; int c2 = 0;
#pragma unroll
        for (int j = 0; j < 32; ++j) {
            if (__float_as_uint(v[j]) > T) { ssum += v[j]; c2++; }
        }
#pragma unroll
        for (int m = 32; m; m >>= 1) {
            ssum += __shfl_xor(ssum, m, 64);
            c2   += __shfl_xor(c2, m, 64);
        }
        if (lane == 0) { rs[wave] = ssum; rc2[wave] = c2; }
        __syncthreads();
        if (tid == 0) {
            float st = 0.f; int ct = 0;
            for (int i = 0; i < 16; ++i) { st += rs[i]; ct += rc2[i]; }
            topk = st + (float)(k - ct) * tval; // ties at T fill remaining slots
        }
    }
    if (tid == 0) {                            // accumulate + last-block finalize
        atomicAdd(sl_tot, sh_sl1);
        atomicAdd(c_tot, sh_cep + topk);
        atomicAdd(np_tot, sh_np);
        __threadfence();
        int d = atomicAdd(done_cnt, 1);
        if (d == NB - 1) {
            float sl = atomicAdd(sl_tot, 0.f);   // coherent reads incl. all contributions
            float cc = atomicAdd(c_tot, 0.f);
            int   np = atomicAdd(np_tot, 0);
            float N = fmaxf((float)np, 1.f);
            out[0] = sl / N;
            out[1] = cc / N;
        }
    }
}

extern "C" void kernel_launch(void* const* d_in, const int* in_sizes, int n_in,
                              void* d_out, int out_size, void* d_ws, size_t ws_size,
                              hipStream_t stream) {
    const float* loc     = (const float*)d_in[0];   // (B,P,4)
    const float* conf    = (const float*)d_in[1];   // (B,P,2)
    const float* priors  = (const float*)d_in[2];   // (P,4)
    const float* targets = (const float*)d_in[3];   // (B,O,5)
    float* out = (float*)d_out;

    char* ws = (char*)d_ws;
    float* mine     = (float*)ws;                       // 4 MB, fully written by K1
    u64*   bpk_part = (u64*)(ws + 4194304);             // 512 KB [b][64][32], fully written by K1
    float* part_sl1 = (float*)(ws + 4718592);           // [b][64] kern1 partials (8 KB each)
    float* part_cep = (float*)(ws + 4726784);
    int*   part_np  = (int*)(ws + 4734976);
    float* sl_tot   = (float*)(ws + 4743168);           // zero-inited by kern1 block (0,0)
    float* c_tot    = (float*)(ws + 4743172);
    int*   np_tot   = (int*)(ws + 4743176);
    int*   done_cnt = (int*)(ws + 4743180);

    dim3 g1(NT1, NB);
    // R17 INSTRUMENTATION: kern1 launched twice (idempotent). wall - 126.96 = t(kern1).
    kern1<<<g1, 256, 0, stream>>>(loc, conf, priors, targets, mine, bpk_part,
                                  part_sl1, part_cep, part_np,
                                  sl_tot, c_tot, np_tot, done_cnt);
    kern1<<<g1, 256, 0, stream>>>(loc, conf, priors, targets, mine, bpk_part,
                                  part_sl1, part_cep, part_np,
                                  sl_tot, c_tot, np_tot, done_cnt);
    kern3<<<NB, 1024, 0, stream>>>(loc, conf, priors, targets, bpk_part, mine,
                                   part_sl1, part_cep, part_np,
                                   sl_tot, c_tot, np_tot, done_cnt, out);
}

// Round 12
// 131.804 us; speedup vs baseline: 1.2193x; 1.2193x over previous
//
#include <hip/hip_runtime.h>
#include <stdint.h>

#define NB 32
#define NP 32768
#define NO 32
#define THRESH 0.35f
#define NT1 64          // kern1 x-tiles (512 priors each)
#define HCOL 33         // kern3 histogram columns (conflict immunity — R4 lesson)

typedef unsigned long long u64;
typedef unsigned int u32;

// fast IoU from prior corners + truth corners. kern1's additions and kern3's
// delta-subtractions must cancel bit-exactly, so BOTH use this helper.
__device__ __forceinline__ float iou_corners(float px1, float py1, float px2, float py2, float ab,
                                             float tx1, float ty1, float tx2, float ty2, float aa)
{
#pragma clang fp contract(off)
    float iw = fminf(tx2, px2) - fmaxf(tx1, px1);
    float ih = fminf(ty2, py2) - fmaxf(ty1, py1);
    iw = fmaxf(iw, 0.f); ih = fmaxf(ih, 0.f);
    float inter = iw * ih;
    return __fdividef(inter, aa + ab - inter);
}

// smooth-L1 of (loc - encode(truth, prior)), summed over 4 coords
__device__ __forceinline__ float smooth_l1_sum(float4 ld, float4 pr, float4 tt)
{
#pragma clang fp contract(off)
    float g0 = __fdividef((tt.x + tt.z) * 0.5f - pr.x, 0.1f * pr.z);
    float g1 = __fdividef((tt.y + tt.w) * 0.5f - pr.y, 0.1f * pr.w);
    float g2 = __logf(__fdividef(tt.z - tt.x, pr.z)) * 5.0f;
    float g3 = __logf(__fdividef(tt.w - tt.y, pr.w)) * 5.0f;
    float d0 = ld.x - g0, d1 = ld.y - g1, d2 = ld.z - g2, d3 = ld.w - g3;
    float a0 = fabsf(d0), a1 = fabsf(d1), a2 = fabsf(d2), a3 = fabsf(d3);
    return (a0 < 1.f ? 0.5f * d0 * d0 : a0 - 0.5f)
         + (a1 < 1.f ? 0.5f * d1 * d1 : a1 - 0.5f)
         + (a2 < 1.f ? 0.5f * d2 * d2 : a2 - 0.5f)
         + (a3 < 1.f ? 0.5f * d3 * d3 : a3 - 0.5f);
}

__device__ __forceinline__ float lse2(float c0, float c1)
{
#pragma clang fp contract(off)
    float mm = fmaxf(c0, c1), mn = fminf(c0, c1);
    return mm + __logf(1.f + __expf(mn - mm));
}

// ---------------- K1: IoU + per-prior best + PRE-FIX losses + mine, all fused ----------
// R18: kern1 measured at 33.8 us (R17 double-launch delta) vs ~10 us VALU floor.
// Theory: DS-pipe bound — staggered o makes tbc[o] b128 reads 4-way bank-conflicted
// (o, o+8, o+16, o+24 alias to the same 4-bank group), ~27 DS cyc/iter/wave; at
// 32 waves/CU that's ~11.5 us of per-CU DS serialization, the dominant term.
// Fix: 4 priors/thread, 128-thread blocks, SAME 64x512 tiles -> total threads
// halve -> total tbc/keys DS reads halve; IoU VALU total unchanged. Occupancy
// 16 waves/CU (fine: per-wave DS demand also halved). kern3 + workspace layout
// UNTOUCHED; mine bits / keys dynamics / pos set / top-k threshold bit-identical.
// Only per-tile fp32 partial grouping changes (absmax ~1e-6..1e-4 << 0.118 thr).
// NOTE: o STAGGER (lane&31) retained — load-bearing for keys[o] atomics (R5).
__global__ __launch_bounds__(128) void kern1(
        const float* __restrict__ loc, const float* __restrict__ conf,
        const float* __restrict__ priors, const float* __restrict__ targets,
        float* __restrict__ mine, u64* __restrict__ bpk_part,
        float* __restrict__ part_sl1, float* __restrict__ part_cep, int* __restrict__ part_np,
        float* __restrict__ sl_tot, float* __restrict__ c_tot,
        int* __restrict__ np_tot, int* __restrict__ done_cnt)
{
#pragma clang fp contract(off)
    __shared__ __align__(16) float4 tbc[NO];   // truth corners
    __shared__ float tlab[NO];
    __shared__ u64 keys[NO];
    __shared__ float rs0[2], rs1[2];
    __shared__ int rc[2];
    const int b = blockIdx.y, x = blockIdx.x, tid = threadIdx.x;
    if (b == 0 && x == 0 && tid == 0) {        // init accumulators for kern3 (runs after us)
        *sl_tot = 0.f; *c_tot = 0.f; *np_tot = 0; *done_cnt = 0;
    }
    for (int e = tid; e < NO * 5; e += 128) {  // 160 entries, 128 threads
        int o = e / 5, c = e % 5;
        float v = targets[b * NO * 5 + e];
        if (c < 4) ((float*)&tbc[o])[c] = v; else tlab[o] = v;
    }
    if (tid < NO) keys[tid] = 0ull;
    __syncthreads();

    const int p0 = x * 512 + tid * 4;          // 4 consecutive priors per thread
    float4 pr[4];
    float px1[4], py1[4], px2[4], py2[4], ab[4];
#pragma unroll
    for (int j = 0; j < 4; ++j) {
        pr[j] = ((const float4*)priors)[p0 + j];
        px1[j] = pr[j].x - pr[j].z * 0.5f;
        py1[j] = pr[j].y - pr[j].w * 0.5f;
        px2[j] = pr[j].x + pr[j].z * 0.5f;
        py2[j] = pr[j].y + pr[j].w * 0.5f;
        ab[j]  = pr[j].z * pr[j].w;
    }
    // per-prior best truth as packed u64: (iou_bits << 6) | (63 - o)
    // max => largest iou, tie => smallest o (reference first-max argmax)
    u64 bk[4] = {0ull, 0ull, 0ull, 0ull};
    const int lane_o = tid & 31;   // stagger (see note above)
    for (int it = 0; it < NO; ++it) {
        const int o = (it + lane_o) & 31;
        float4 tt = tbc[o];
        float aa = (tt.z - tt.x) * (tt.w - tt.y);   // inline area
        float iou4[4];
#pragma unroll
        for (int j = 0; j < 4; ++j) {
            float iou = iou_corners(px1[j], py1[j], px2[j], py2[j], ab[j],
                                    tt.x, tt.y, tt.z, tt.w, aa);
            iou4[j] = iou;
            u64 ko = ((u64)__float_as_uint(iou) << 6) | (u64)(63 - o);
            bk[j] = bk[j] > ko ? bk[j] : ko;
        }
        // per-truth best prior: cheap value-only filter, rare full path
        float vm = fmaxf(fmaxf(iou4[0], iou4[1]), fmaxf(iou4[2], iou4[3]));
        u64 cur = keys[o];
        if (__float_as_uint(vm) > (u32)(cur >> 32)) {
            // descending scan with >= keeps the SMALLEST prior index on ties
            float bi = iou4[3]; int bp = p0 + 3;
            if (iou4[2] >= bi) { bi = iou4[2]; bp = p0 + 2; }
            if (iou4[1] >= bi) { bi = iou4[1]; bp = p0 + 1; }
            if (iou4[0] >= bi) { bi = iou4[0]; bp = p0; }
            atomicMax(&keys[o], ((u64)__float_as_uint(bi) << 32) | (u64)(~(u32)bp));
        }
    }

    // ---- pre-fix losses straight from registers ----
    const size_t gbase = (size_t)b * NP + p0;
    float4 cfA = ((const float4*)conf)[gbase >> 1];        // priors p0, p0+1
    float4 cfB = ((const float4*)conf)[(gbase >> 1) + 1];  // priors p0+2, p0+3
    float c0[4] = {cfA.x, cfA.z, cfB.x, cfB.z};
    float c1[4] = {cfA.y, cfA.w, cfB.y, cfB.w};
    float4 mout;
    float s_sl1 = 0.f, s_cep = 0.f;
    int np = 0;
#pragma unroll
    for (int j = 0; j < 4; ++j) {
        u32 vb = (u32)(bk[j] >> 6);
        float bv = __uint_as_float(vb);
        int o = 63 - (int)(bk[j] & 63);
        int cfv = (bv < THRESH) ? 0 : ((int)tlab[o] + 1);
        bool pos = cfv > 0;
        float ce = lse2(c0[j], c1[j]) - ((cfv == 0) ? c0[j] : c1[j]);
        if (pos) {                                  // exec-masked: no loc fetch, no sl1
            float4 ld = ((const float4*)loc)[gbase + j];   // math for ~99% of priors
            s_sl1 += smooth_l1_sum(ld, pr[j], tbc[o]);
            s_cep += ce;
            np++;
        }
        ((float*)&mout)[j] = pos ? 0.f : ce;
    }
    ((float4*)mine)[gbase >> 2] = mout;

#pragma unroll
    for (int m = 32; m; m >>= 1) {
        s_sl1 += __shfl_xor(s_sl1, m, 64);
        s_cep += __shfl_xor(s_cep, m, 64);
        np    += __shfl_xor(np, m, 64);
    }
    int lane = tid & 63, w = tid >> 6;             // 2 waves per block
    if (lane == 0) { rs0[w] = s_sl1; rs1[w] = s_cep; rc[w] = np; }
    __syncthreads();
    if (tid == 0) {
        part_sl1[b * NT1 + x] = rs0[0] + rs0[1];
        part_cep[b * NT1 + x] = rs1[0] + rs1[1];
        part_np [b * NT1 + x] = rc[0] + rc[1];
    }
    if (tid < NO) bpk_part[(b * NT1 + x) * 32 + tid] = keys[tid];  // after the sync above
}

// ---------------- K3: wave-specialized fix + column radix-select top-k + finalize ------
// R11: kern3 is ONE block/batch on ONE CU -> everything serializes per-CU. All 16
// waves issue v loads FIRST (per-wave vmcnt drain at the barrier), then WAVE 15
// ALONE does targets->tbc, parallel bpk resolve (64 lanes x 32 loads all in
// flight), and the fix phase -- all within-wave, hidden UNDER the other waves'
// load drain. Fix precedes pass-0, so the histogram is built on post-fix values
// directly. Sum trees bit-identical to verified versions. UNCHANGED this round.
__global__ __launch_bounds__(1024) void kern3(
        const float* __restrict__ loc, const float* __restrict__ conf,
        const float* __restrict__ priors, const float* __restrict__ targets,
        const u64* __restrict__ bpk_part, const float* __restrict__ mine,
        const float* __restrict__ part_sl1, const float* __restrict__ part_cep,
        const int* __restrict__ part_np,
        float* __restrict__ sl_tot, float* __restrict__ c_tot,
        int* __restrict__ np_tot, int* __restrict__ done_cnt,
        float* __restrict__ out)
{
#pragma clang fp contract(off)
    const int b = blockIdx.x, tid = threadIdx.x;
    const int wave = tid >> 6, lane = tid & 63;
    const int cl = lane & 31;                   // histogram column
    __shared__ __align__(16) float4 tbc[NO];
    __shared__ float tlab[NO], tas[NO];
    __shared__ u32 pp_s[NO];
    __shared__ u32 flags[1024];                 // 32768-bit mask of forced priors
    __shared__ int hA[256 * HCOL], hB[256 * HCOL];  // 66 KB ping-pong column hists
    __shared__ float dslA[NO], dceA[NO];
    __shared__ int dnpA[NO];
    __shared__ int wtot[4];
    __shared__ float rs[16];
    __shared__ int rc2[16];
    __shared__ float sh_sl1, sh_cep;
    __shared__ int sh_np, sh_k, sh_kk;
    __shared__ u32 sh_prefix;

    // ---- all waves: issue the mine loads FIRST (each wave drains only its own) ----
    const float* mb = mine + (size_t)b * NP;
    float v[32];
#pragma unroll
    for (int q = 0; q < 8; ++q) {
        float4 t4 = ((const float4*)mb)[q * 1024 + tid];
        v[4 * q] = t4.x; v[4 * q + 1] = t4.y; v[4 * q + 2] = t4.z; v[4 * q + 3] = t4.w;
    }

    if (wave < 15) {
        // clears only; these waves then sit at the barrier while their loads drain
        for (int i = tid; i < 256 * HCOL; i += 960) { hA[i] = 0; hB[i] = 0; }
    } else {
        // ---- wave 15: serial front-half, overlapped under the other waves' drain ----
        // flags clear (wave-15-owned: no race with its own later atomicOr)
        for (int i = lane; i < 1024; i += 64) flags[i] = 0u;
        // targets: 160 floats via 3 loads/lane
        float tv0 = targets[b * NO * 5 + lane];
        float tv1 = targets[b * NO * 5 + 64 + lane];
        float tv2 = (lane < 32) ? targets[b * NO * 5 + 128 + lane] : 0.f;
        // bpk resolve: lane = o + 32*h handles xx in [32h, 32h+32) -> all loads in flight
        const int ro = lane & 31, rh = lane >> 5;
        const u64* bp = bpk_part + ((size_t)(b * NT1 + rh * 32)) * 32 + ro;
        u64 key = 0ull;
#pragma unroll
        for (int j = 0; j < 32; ++j) {
            u64 t2 = bp[(size_t)j * 32];
            key = t2 > key ? t2 : key;
        }
        // scatter targets to LDS (same-wave lgkmcnt ordering; no block barrier needed)
        {
            int e = lane;       int o = e / 5, c = e % 5;
            if (c < 4) ((float*)&tbc[o])[c] = tv0; else tlab[o] = tv0;
            e = lane + 64;      o = e / 5;  c = e % 5;
            if (c < 4) ((float*)&tbc[o])[c] = tv1; else tlab[o] = tv1;
            if (lane < 32) {
                e = lane + 128; o = e / 5;  c = e % 5;
                if (c < 4) ((float*)&tbc[o])[c] = tv2; else tlab[o] = tv2;
            }
        }
        if (lane < NO) {
            float4 t = tbc[lane];
            tas[lane] = (t.z - t.x) * (t.w - t.y);
        }
        // combine resolve halves across the wave (lane o <-> o+32)
        {
            u64 t2 = __shfl_xor(key, 32, 64);
            key = t2 > key ? t2 : key;
        }
        u32 ppv = (key >> 32) ? ~(u32)key : 0u;     // all-zero row => argmax = 0
        if (lane < NO) pp_s[lane] = ppv;
        // ---- fix phase: lane = o, serial IoU loop (old A2 body, verbatim math) ----
        if (lane < NO) {
            const int o = lane;
            const u32 p = ppv;
            float dsl1 = 0.f, dcep = 0.f; int dnp = 0;
            bool last = true;
            for (int o2 = o + 1; o2 < NO; ++o2)
                if (pp_s[o2] == p) { last = false; break; }   // later o overwrites same prior
            if (last) {
                float4 prr = ((const float4*)priors)[p];
                float px1 = prr.x - prr.z * 0.5f, py1 = prr.y - prr.w * 0.5f;
                float px2 = prr.x + prr.z * 0.5f, py2 = prr.y + prr.w * 0.5f;
                float ab = prr.z * prr.w;
                // pre-fix best truth for p (natural order, strict > == first-max)
                float bv = -1.f; int bo_ = 0;
                for (int o2 = 0; o2 < NO; ++o2) {
                    float4 t2 = tbc[o2];
                    float i2 = iou_corners(px1, py1, px2, py2, ab, t2.x, t2.y, t2.z, t2.w, tas[o2]);
                    if (i2 > bv) { bv = i2; bo_ = o2; }
                }
                int cf_pre = (bv < THRESH) ? 0 : ((int)tlab[bo_] + 1);
                size_t gp = (size_t)b * NP + p;
                float4 ld = ((const float4*)loc)[gp];
                float2 c = ((const float2*)conf)[gp];
                float lse = lse2(c.x, c.y);
                int cf_new = (int)tlab[o] + 1;               // forced positive
                dsl1 = smooth_l1_sum(ld, prr, tbc[o]);
                dcep = lse - ((cf_new == 0) ? c.x : c.y);
                dnp = 1;
                if (cf_pre > 0) {                            // remove pre-fix contribution
                    dsl1 -= smooth_l1_sum(ld, prr, tbc[bo_]);
                    dcep -= lse - ((cf_pre == 0) ? c.x : c.y);
                    dnp = 0;
                }
                atomicOr(&flags[p >> 5], 1u << (p & 31));
            }
            dslA[o] = dsl1; dceA[o] = dcep; dnpA[o] = dnp;
        }
    }
    __syncthreads();   // B1: v in regs, tbc/tas/pp/flags/deltas ready

    // ---- A3: zero forced v in-register, then pass-0 histogram on POST-fix values ----
#pragma unroll
    for (int q = 0; q < 8; ++q) {
        u32 word = flags[q * 128 + (tid >> 3)];
#pragma unroll
        for (int c = 0; c < 4; ++c)
            if ((word >> (((tid & 7) << 2) + c)) & 1u) v[4 * q + c] = 0.f;
    }
#pragma unroll 8
    for (int j = 0; j < 32; ++j)
        atomicAdd(&hA[(__float_as_uint(v[j]) >> 24) * HCOL + cl], 1);
    // batch stats (same order/tree as verified versions -> bit-identical)
    if (tid < NO) {
        float a = part_sl1[b * NT1 + tid] + part_sl1[b * NT1 + 32 + tid] + dslA[tid];
        float d = part_cep[b * NT1 + tid] + part_cep[b * NT1 + 32 + tid] + dceA[tid];
        int   n = part_np [b * NT1 + tid] + part_np [b * NT1 + 32 + tid] + dnpA[tid];
#pragma unroll
        for (int m = 16; m; m >>= 1) {
            a += __shfl_xor(a, m, 32);
            d += __shfl_xor(d, m, 32);
            n += __shfl_xor(n, m, 32);
        }
        if (tid == 0) {
            sh_sl1 = a; sh_cep = d; sh_np = n;
            sh_k = min(7 * n, NP - 1); sh_kk = sh_k; sh_prefix = 0u;
        }
    }
    __syncthreads();   // B2: hist + k ready

    const int k = sh_k;
    float topk = 0.f;
    if (k > 0) {
        for (int pass = 0; pass < 4; ++pass) {
            int* cur = (pass & 1) ? hB : hA;
            if (pass > 0) {
                // sparse survivor atomics into cur; overlap clear of the dead buffer
                const int shift = 24 - 8 * pass;
                const u32 pfx = sh_prefix;
#pragma unroll 8
                for (int j = 0; j < 32; ++j) {
                    u32 kb = __float_as_uint(v[j]);
                    if ((u32)(((u64)kb) >> (shift + 8)) == pfx)   // 64-bit shift: defined at 32
                        atomicAdd(&cur[((kb >> shift) & 255) * HCOL + cl], 1);
                }
                if (pass < 3) {                  // other buffer is dead (its scan done);
                    int* other = (pass & 1) ? hA : hB;   // it is cur two passes later
                    for (int i = tid; i < 256 * HCOL; i += 1024) other[i] = 0;
                }
                __syncthreads();
            }
            // merged reduce+scan: thread==bin sums 33 cols + in-wave suffix
            int tot = 0, suf = 0;
            if (tid < 256) {
                const int hb = tid * HCOL;
#pragma unroll
                for (int i = 0; i < HCOL; ++i) tot += cur[hb + i];   // stride 33: no conflicts
                suf = tot;
#pragma unroll
                for (int off = 1; off < 64; off <<= 1) {
                    int u = __shfl_down(suf, off, 64);
                    if (lane + off < 64) suf += u;   // inclusive suffix over higher lanes
                }
                if (lane == 0) wtot[wave] = suf;
            }
            __syncthreads();
            // boundary: unique bin with excl < kk <= excl+tot (suffix order = descending)
            if (tid < 256) {
                int excl = suf - tot;
                for (int w2 = wave + 1; w2 < 4; ++w2) excl += wtot[w2];
                int kk = sh_kk;
                if (excl < kk && kk <= excl + tot) {
                    sh_prefix = (sh_prefix << 8) | (u32)tid;
                    sh_kk = kk - excl;
                }
            }
            __syncthreads();
        }
        // ---- F: sum of strictly-greater + tie fill (identical to verified versions) ----
        const u32 T = sh_prefix;                // exact k-th largest key
        const float tval = __uint_as_float(T);
        float ssum = 0.f; int c2 = 0;
#pragma unroll
        for (int j = 0; j < 32; ++j) {
            if (__float_as_uint(v[j]) > T) { ssum += v[j]; c2++; }
        }
#pragma unroll
        for (int m = 32; m; m >>= 1) {
            ssum += __shfl_xor(ssum, m, 64);
            c2   += __shfl_xor(c2, m, 64);
        }
        if (lane == 0) { rs[wave] = ssum; rc2[wave] = c2; }
        __syncthreads();
        if (tid == 0) {
            float st = 0.f; int ct = 0;
            for (int i = 0; i < 16; ++i) { st += rs[i]; ct += rc2[i]; }
            topk = st + (float)(k - ct) * tval; // ties at T fill remaining slots
        }
    }
    if (tid == 0) {                            // accumulate + last-block finalize
        atomicAdd(sl_tot, sh_sl1);
        atomicAdd(c_tot, sh_cep + topk);
        atomicAdd(np_tot, sh_np);
        __threadfence();
        int d = atomicAdd(done_cnt, 1);
        if (d == NB - 1) {
            float sl = atomicAdd(sl_tot, 0.f);   // coherent reads incl. all contributions
            float cc = atomicAdd(c_tot, 0.f);
            int   np = atomicAdd(np_tot, 0);
            float N = fmaxf((float)np, 1.f);
            out[0] = sl / N;
            out[1] = cc / N;
        }
    }
}

extern "C" void kernel_launch(void* const* d_in, const int* in_sizes, int n_in,
                              void* d_out, int out_size, void* d_ws, size_t ws_size,
                              hipStream_t stream) {
    const float* loc     = (const float*)d_in[0];   // (B,P,4)
    const float* conf    = (const float*)d_in[1];   // (B,P,2)
    const float* priors  = (const float*)d_in[2];   // (P,4)
    const float* targets = (const float*)d_in[3];   // (B,O,5)
    float* out = (float*)d_out;

    char* ws = (char*)d_ws;
    float* mine     = (float*)ws;                       // 4 MB, fully written by K1
    u64*   bpk_part = (u64*)(ws + 4194304);             // 512 KB [b][64][32], fully written by K1
    float* part_sl1 = (float*)(ws + 4718592);           // [b][64] kern1 partials (8 KB each)
    float* part_cep = (float*)(ws + 4726784);
    int*   part_np  = (int*)(ws + 4734976);
    float* sl_tot   = (float*)(ws + 4743168);           // zero-inited by kern1 block (0,0)
    float* c_tot    = (float*)(ws + 4743172);
    int*   np_tot   = (int*)(ws + 4743176);
    int*   done_cnt = (int*)(ws + 4743180);

    dim3 g1(NT1, NB);
    kern1<<<g1, 128, 0, stream>>>(loc, conf, priors, targets, mine, bpk_part,
                                  part_sl1, part_cep, part_np,
                                  sl_tot, c_tot, np_tot, done_cnt);
    kern3<<<NB, 1024, 0, stream>>>(loc, conf, priors, targets, bpk_part, mine,
                                   part_sl1, part_cep, part_np,
                                   sl_tot, c_tot, np_tot, done_cnt, out);
}

// Round 13
// 125.574 us; speedup vs baseline: 1.2798x; 1.0496x over previous
//
#include <hip/hip_runtime.h>
#include <stdint.h>

#define NB 32
#define NP 32768
#define NO 32
#define THRESH 0.35f
#define NT1 64          // kern1 x-tiles (512 priors each)
#define HCOL 33         // kern3 histogram columns (conflict immunity — R4 lesson)

typedef unsigned long long u64;
typedef unsigned int u32;

// fast IoU from prior corners + truth corners. kern1's additions and kern3's
// delta-subtractions must cancel bit-exactly, so BOTH use this helper.
__device__ __forceinline__ float iou_corners(float px1, float py1, float px2, float py2, float ab,
                                             float tx1, float ty1, float tx2, float ty2, float aa)
{
#pragma clang fp contract(off)
    float iw = fminf(tx2, px2) - fmaxf(tx1, px1);
    float ih = fminf(ty2, py2) - fmaxf(ty1, py1);
    iw = fmaxf(iw, 0.f); ih = fmaxf(ih, 0.f);
    float inter = iw * ih;
    return __fdividef(inter, aa + ab - inter);
}

// smooth-L1 of (loc - encode(truth, prior)), summed over 4 coords
__device__ __forceinline__ float smooth_l1_sum(float4 ld, float4 pr, float4 tt)
{
#pragma clang fp contract(off)
    float g0 = __fdividef((tt.x + tt.z) * 0.5f - pr.x, 0.1f * pr.z);
    float g1 = __fdividef((tt.y + tt.w) * 0.5f - pr.y, 0.1f * pr.w);
    float g2 = __logf(__fdividef(tt.z - tt.x, pr.z)) * 5.0f;
    float g3 = __logf(__fdividef(tt.w - tt.y, pr.w)) * 5.0f;
    float d0 = ld.x - g0, d1 = ld.y - g1, d2 = ld.z - g2, d3 = ld.w - g3;
    float a0 = fabsf(d0), a1 = fabsf(d1), a2 = fabsf(d2), a3 = fabsf(d3);
    return (a0 < 1.f ? 0.5f * d0 * d0 : a0 - 0.5f)
         + (a1 < 1.f ? 0.5f * d1 * d1 : a1 - 0.5f)
         + (a2 < 1.f ? 0.5f * d2 * d2 : a2 - 0.5f)
         + (a3 < 1.f ? 0.5f * d3 * d3 : a3 - 0.5f);
}

__device__ __forceinline__ float lse2(float c0, float c1)
{
#pragma clang fp contract(off)
    float mm = fmaxf(c0, c1), mn = fminf(c0, c1);
    return mm + __logf(1.f + __expf(mn - mm));
}

// ---------------- K1: IoU + per-prior best + PRE-FIX losses + mine, all fused ----------
// grid (64 tiles, 32 batches) x 256 threads; each thread owns 2 CONSECUTIVE priors.
// 2048 blocks -> 8 blocks/CU -> 32 waves/CU. o STAGGERED per lane (R5: load-bearing
// for keys[o] atomic spread).
// R19: kern1 counters (R18, first sighting): VALUBusy 75.6%, LDS_BANK_CONFLICT 267K
// (trivial), HBM 4.4% -> VALU-ISSUE-BOUND. R18's DS-halving (4 priors/128thr)
// regressed 33.8->44.0 via occupancy loss; REVERTED to 256-thr geometry. New:
// per-prior best-truth tracking switched from u64 pack/max (lshl_b64+or+cmp_u64+
// 2 cndmask ~6 VALU) to float+idx (cmp_gt+2 cndmask = 3 VALU). Tie semantics:
// positive-IoU exact ties across truths are measure-zero for continuous random
// boxes; all-zero rows pick arbitrary o which provably doesn't affect outputs
// (bv=0<THRESH -> conf=0, mine=ce (o-free), sl1 skipped). keys[] u64 pack (cross-
// tile per-truth best prior; feeds forced-positive fix) UNCHANGED — exactness kept.
__global__ __launch_bounds__(256) void kern1(
        const float* __restrict__ loc, const float* __restrict__ conf,
        const float* __restrict__ priors, const float* __restrict__ targets,
        float* __restrict__ mine, u64* __restrict__ bpk_part,
        float* __restrict__ part_sl1, float* __restrict__ part_cep, int* __restrict__ part_np,
        float* __restrict__ sl_tot, float* __restrict__ c_tot,
        int* __restrict__ np_tot, int* __restrict__ done_cnt)
{
#pragma clang fp contract(off)
    __shared__ __align__(16) float4 tbc[NO];   // truth corners
    __shared__ float tlab[NO];
    __shared__ u64 keys[NO];
    __shared__ float rs0[4], rs1[4];
    __shared__ int rc[4];
    const int b = blockIdx.y, x = blockIdx.x, tid = threadIdx.x;
    if (b == 0 && x == 0 && tid == 0) {        // init accumulators for kern3 (runs after us)
        *sl_tot = 0.f; *c_tot = 0.f; *np_tot = 0; *done_cnt = 0;
    }
    if (tid < NO * 5) {
        int o = tid / 5, c = tid % 5;
        float v = targets[b * NO * 5 + tid];
        if (c < 4) ((float*)&tbc[o])[c] = v; else tlab[o] = v;
    }
    if (tid < NO) keys[tid] = 0ull;
    __syncthreads();

    const int p0 = x * 512 + tid * 2;
    float4 pr[2];
    float px1[2], py1[2], px2[2], py2[2], ab[2];
#pragma unroll
    for (int j = 0; j < 2; ++j) {
        pr[j] = ((const float4*)priors)[p0 + j];
        px1[j] = pr[j].x - pr[j].z * 0.5f;
        py1[j] = pr[j].y - pr[j].w * 0.5f;
        px2[j] = pr[j].x + pr[j].z * 0.5f;
        py2[j] = pr[j].y + pr[j].w * 0.5f;
        ab[j]  = pr[j].z * pr[j].w;
    }
    // per-prior best truth: float value + index (3-VALU update; see R19 note)
    float bi[2] = {-1.f, -1.f};
    int bo[2] = {0, 0};
    const int lane_o = tid & 31;   // stagger (see note above)
    for (int it = 0; it < NO; ++it) {
        const int o = (it + lane_o) & 31;
        float4 tt = tbc[o];
        float aa = (tt.z - tt.x) * (tt.w - tt.y);   // inline area
        float iou2[2];
#pragma unroll
        for (int j = 0; j < 2; ++j) {
            float iou = iou_corners(px1[j], py1[j], px2[j], py2[j], ab[j],
                                    tt.x, tt.y, tt.z, tt.w, aa);
            iou2[j] = iou;
            bool gt = iou > bi[j];
            bi[j] = gt ? iou : bi[j];
            bo[j] = gt ? o : bo[j];
        }
        // per-truth best prior: cheap value-only filter, rare full path
        // (u64 pack kept here: cross-tile argmax must be exact incl. tie->smallest p)
        float vm = fmaxf(iou2[0], iou2[1]);
        u64 cur = keys[o];
        if (__float_as_uint(vm) > (u32)(cur >> 32)) {
            float bi2 = iou2[1]; int bp = p0 + 1;
            if (iou2[0] >= bi2) { bi2 = iou2[0]; bp = p0; }
            atomicMax(&keys[o], ((u64)__float_as_uint(bi2) << 32) | (u64)(~(u32)bp));
        }
    }

    // ---- pre-fix losses straight from registers ----
    const size_t gbase = (size_t)b * NP + p0;
    float4 cf = ((const float4*)conf)[gbase >> 1];
    float c0[2] = {cf.x, cf.z};
    float c1[2] = {cf.y, cf.w};
    float2 mout;
    float s_sl1 = 0.f, s_cep = 0.f;
    int np = 0;
#pragma unroll
    for (int j = 0; j < 2; ++j) {
        float bv = bi[j];
        int o = bo[j];
        int cfv = (bv < THRESH) ? 0 : ((int)tlab[o] + 1);
        bool pos = cfv > 0;
        float ce = lse2(c0[j], c1[j]) - ((cfv == 0) ? c0[j] : c1[j]);
        if (pos) {                                  // exec-masked: no loc fetch, no sl1
            float4 ld = ((const float4*)loc)[gbase + j];   // math for ~99% of priors
            s_sl1 += smooth_l1_sum(ld, pr[j], tbc[o]);
            s_cep += ce;
            np++;
        }
        ((float*)&mout)[j] = pos ? 0.f : ce;
    }
    ((float2*)mine)[gbase >> 1] = mout;

#pragma unroll
    for (int m = 32; m; m >>= 1) {
        s_sl1 += __shfl_xor(s_sl1, m, 64);
        s_cep += __shfl_xor(s_cep, m, 64);
        np    += __shfl_xor(np, m, 64);
    }
    int lane = tid & 63, w = tid >> 6;
    if (lane == 0) { rs0[w] = s_sl1; rs1[w] = s_cep; rc[w] = np; }
    __syncthreads();
    if (tid == 0) {
        float t0 = 0.f, t1 = 0.f; int t2 = 0;
        for (int i = 0; i < 4; ++i) { t0 += rs0[i]; t1 += rs1[i]; t2 += rc[i]; }
        part_sl1[b * NT1 + x] = t0;
        part_cep[b * NT1 + x] = t1;
        part_np [b * NT1 + x] = t2;
    }
    if (tid < NO) bpk_part[(b * NT1 + x) * 32 + tid] = keys[tid];  // after the sync above
}

// ---------------- K3: wave-specialized fix + column radix-select top-k + finalize ------
// R11: kern3 is ONE block/batch on ONE CU -> everything serializes per-CU. All 16
// waves issue v loads FIRST (per-wave vmcnt drain at the barrier), then WAVE 15
// ALONE does targets->tbc, parallel bpk resolve (64 lanes x 32 loads all in
// flight), and the fix phase -- all within-wave, hidden UNDER the other waves'
// load drain. Fix precedes pass-0, so the histogram is built on post-fix values
// directly. Sum trees bit-identical to verified versions. UNCHANGED this round.
__global__ __launch_bounds__(1024) void kern3(
        const float* __restrict__ loc, const float* __restrict__ conf,
        const float* __restrict__ priors, const float* __restrict__ targets,
        const u64* __restrict__ bpk_part, const float* __restrict__ mine,
        const float* __restrict__ part_sl1, const float* __restrict__ part_cep,
        const int* __restrict__ part_np,
        float* __restrict__ sl_tot, float* __restrict__ c_tot,
        int* __restrict__ np_tot, int* __restrict__ done_cnt,
        float* __restrict__ out)
{
#pragma clang fp contract(off)
    const int b = blockIdx.x, tid = threadIdx.x;
    const int wave = tid >> 6, lane = tid & 63;
    const int cl = lane & 31;                   // histogram column
    __shared__ __align__(16) float4 tbc[NO];
    __shared__ float tlab[NO], tas[NO];
    __shared__ u32 pp_s[NO];
    __shared__ u32 flags[1024];                 // 32768-bit mask of forced priors
    __shared__ int hA[256 * HCOL], hB[256 * HCOL];  // 66 KB ping-pong column hists
    __shared__ float dslA[NO], dceA[NO];
    __shared__ int dnpA[NO];
    __shared__ int wtot[4];
    __shared__ float rs[16];
    __shared__ int rc2[16];
    __shared__ float sh_sl1, sh_cep;
    __shared__ int sh_np, sh_k, sh_kk;
    __shared__ u32 sh_prefix;

    // ---- all waves: issue the mine loads FIRST (each wave drains only its own) ----
    const float* mb = mine + (size_t)b * NP;
    float v[32];
#pragma unroll
    for (int q = 0; q < 8; ++q) {
        float4 t4 = ((const float4*)mb)[q * 1024 + tid];
        v[4 * q] = t4.x; v[4 * q + 1] = t4.y; v[4 * q + 2] = t4.z; v[4 * q + 3] = t4.w;
    }

    if (wave < 15) {
        // clears only; these waves then sit at the barrier while their loads drain
        for (int i = tid; i < 256 * HCOL; i += 960) { hA[i] = 0; hB[i] = 0; }
    } else {
        // ---- wave 15: serial front-half, overlapped under the other waves' drain ----
        // flags clear (wave-15-owned: no race with its own later atomicOr)
        for (int i = lane; i < 1024; i += 64) flags[i] = 0u;
        // targets: 160 floats via 3 loads/lane
        float tv0 = targets[b * NO * 5 + lane];
        float tv1 = targets[b * NO * 5 + 64 + lane];
        float tv2 = (lane < 32) ? targets[b * NO * 5 + 128 + lane] : 0.f;
        // bpk resolve: lane = o + 32*h handles xx in [32h, 32h+32) -> all loads in flight
        const int ro = lane & 31, rh = lane >> 5;
        const u64* bp = bpk_part + ((size_t)(b * NT1 + rh * 32)) * 32 + ro;
        u64 key = 0ull;
#pragma unroll
        for (int j = 0; j < 32; ++j) {
            u64 t2 = bp[(size_t)j * 32];
            key = t2 > key ? t2 : key;
        }
        // scatter targets to LDS (same-wave lgkmcnt ordering; no block barrier needed)
        {
            int e = lane;       int o = e / 5, c = e % 5;
            if (c < 4) ((float*)&tbc[o])[c] = tv0; else tlab[o] = tv0;
            e = lane + 64;      o = e / 5;  c = e % 5;
            if (c < 4) ((float*)&tbc[o])[c] = tv1; else tlab[o] = tv1;
            if (lane < 32) {
                e = lane + 128; o = e / 5;  c = e % 5;
                if (c < 4) ((float*)&tbc[o])[c] = tv2; else tlab[o] = tv2;
            }
        }
        if (lane < NO) {
            float4 t = tbc[lane];
            tas[lane] = (t.z - t.x) * (t.w - t.y);
        }
        // combine resolve halves across the wave (lane o <-> o+32)
        {
            u64 t2 = __shfl_xor(key, 32, 64);
            key = t2 > key ? t2 : key;
        }
        u32 ppv = (key >> 32) ? ~(u32)key : 0u;     // all-zero row => argmax = 0
        if (lane < NO) pp_s[lane] = ppv;
        // ---- fix phase: lane = o, serial IoU loop (old A2 body, verbatim math) ----
        if (lane < NO) {
            const int o = lane;
            const u32 p = ppv;
            float dsl1 = 0.f, dcep = 0.f; int dnp = 0;
            bool last = true;
            for (int o2 = o + 1; o2 < NO; ++o2)
                if (pp_s[o2] == p) { last = false; break; }   // later o overwrites same prior
            if (last) {
                float4 prr = ((const float4*)priors)[p];
                float px1 = prr.x - prr.z * 0.5f, py1 = prr.y - prr.w * 0.5f;
                float px2 = prr.x + prr.z * 0.5f, py2 = prr.y + prr.w * 0.5f;
                float ab = prr.z * prr.w;
                // pre-fix best truth for p (natural order, strict > == first-max)
                float bv = -1.f; int bo_ = 0;
                for (int o2 = 0; o2 < NO; ++o2) {
                    float4 t2 = tbc[o2];
                    float i2 = iou_corners(px1, py1, px2, py2, ab, t2.x, t2.y, t2.z, t2.w, tas[o2]);
                    if (i2 > bv) { bv = i2; bo_ = o2; }
                }
                int cf_pre = (bv < THRESH) ? 0 : ((int)tlab[bo_] + 1);
                size_t gp = (size_t)b * NP + p;
                float4 ld = ((const float4*)loc)[gp];
                float2 c = ((const float2*)conf)[gp];
                float lse = lse2(c.x, c.y);
                int cf_new = (int)tlab[o] + 1;               // forced positive
                dsl1 = smooth_l1_sum(ld, prr, tbc[o]);
                dcep = lse - ((cf_new == 0) ? c.x : c.y);
                dnp = 1;
                if (cf_pre > 0) {                            // remove pre-fix contribution
                    dsl1 -= smooth_l1_sum(ld, prr, tbc[bo_]);
                    dcep -= lse - ((cf_pre == 0) ? c.x : c.y);
                    dnp = 0;
                }
                atomicOr(&flags[p >> 5], 1u << (p & 31));
            }
            dslA[o] = dsl1; dceA[o] = dcep; dnpA[o] = dnp;
        }
    }
    __syncthreads();   // B1: v in regs, tbc/tas/pp/flags/deltas ready

    // ---- A3: zero forced v in-register, then pass-0 histogram on POST-fix values ----
#pragma unroll
    for (int q = 0; q < 8; ++q) {
        u32 word = flags[q * 128 + (tid >> 3)];
#pragma unroll
        for (int c = 0; c < 4; ++c)
            if ((word >> (((tid & 7) << 2) + c)) & 1u) v[4 * q + c] = 0.f;
    }
#pragma unroll 8
    for (int j = 0; j < 32; ++j)
        atomicAdd(&hA[(__float_as_uint(v[j]) >> 24) * HCOL + cl], 1);
    // batch stats (same order/tree as verified versions -> bit-identical)
    if (tid < NO) {
        float a = part_sl1[b * NT1 + tid] + part_sl1[b * NT1 + 32 + tid] + dslA[tid];
        float d = part_cep[b * NT1 + tid] + part_cep[b * NT1 + 32 + tid] + dceA[tid];
        int   n = part_np [b * NT1 + tid] + part_np [b * NT1 + 32 + tid] + dnpA[tid];
#pragma unroll
        for (int m = 16; m; m >>= 1) {
            a += __shfl_xor(a, m, 32);
            d += __shfl_xor(d, m, 32);
            n += __shfl_xor(n, m, 32);
        }
        if (tid == 0) {
            sh_sl1 = a; sh_cep = d; sh_np = n;
            sh_k = min(7 * n, NP - 1); sh_kk = sh_k; sh_prefix = 0u;
        }
    }
    __syncthreads();   // B2: hist + k ready

    const int k = sh_k;
    float topk = 0.f;
    if (k > 0) {
        for (int pass = 0; pass < 4; ++pass) {
            int* cur = (pass & 1) ? hB : hA;
            if (pass > 0) {
                // sparse survivor atomics into cur; overlap clear of the dead buffer
                const int shift = 24 - 8 * pass;
                const u32 pfx = sh_prefix;
#pragma unroll 8
                for (int j = 0; j < 32; ++j) {
                    u32 kb = __float_as_uint(v[j]);
                    if ((u32)(((u64)kb) >> (shift + 8)) == pfx)   // 64-bit shift: defined at 32
                        atomicAdd(&cur[((kb >> shift) & 255) * HCOL + cl], 1);
                }
                if (pass < 3) {                  // other buffer is dead (its scan done);
                    int* other = (pass & 1) ? hA : hB;   // it is cur two passes later
                    for (int i = tid; i < 256 * HCOL; i += 1024) other[i] = 0;
                }
                __syncthreads();
            }
            // merged reduce+scan: thread==bin sums 33 cols + in-wave suffix
            int tot = 0, suf = 0;
            if (tid < 256) {
                const int hb = tid * HCOL;
#pragma unroll
                for (int i = 0; i < HCOL; ++i) tot += cur[hb + i];   // stride 33: no conflicts
                suf = tot;
#pragma unroll
                for (int off = 1; off < 64; off <<= 1) {
                    int u = __shfl_down(suf, off, 64);
                    if (lane + off < 64) suf += u;   // inclusive suffix over higher lanes
                }
                if (lane == 0) wtot[wave] = suf;
            }
            __syncthreads();
            // boundary: unique bin with excl < kk <= excl+tot (suffix order = descending)
            if (tid < 256) {
                int excl = suf - tot;
                for (int w2 = wave + 1; w2 < 4; ++w2) excl += wtot[w2];
                int kk = sh_kk;
                if (excl < kk && kk <= excl + tot) {
                    sh_prefix = (sh_prefix << 8) | (u32)tid;
                    sh_kk = kk - excl;
                }
            }
            __syncthreads();
        }
        // ---- F: sum of strictly-greater + tie fill (identical to verified versions) ----
        const u32 T = sh_prefix;                // exact k-th largest key
        const float tval = __uint_as_float(T);
        float ssum = 0.f; int c2 = 0;
#pragma unroll
        for (int j = 0; j < 32; ++j) {
            if (__float_as_uint(v[j]) > T) { ssum += v[j]; c2++; }
        }
#pragma unroll
        for (int m = 32; m; m >>= 1) {
            ssum += __shfl_xor(ssum, m, 64);
            c2   += __shfl_xor(c2, m, 64);
        }
        if (lane == 0) { rs[wave] = ssum; rc2[wave] = c2; }
        __syncthreads();
        if (tid == 0) {
            float st = 0.f; int ct = 0;
            for (int i = 0; i < 16; ++i) { st += rs[i]; ct += rc2[i]; }
            topk = st + (float)(k - ct) * tval; // ties at T fill remaining slots
        }
    }
    if (tid == 0) {                            // accumulate + last-block finalize
        atomicAdd(sl_tot, sh_sl1);
        atomicAdd(c_tot, sh_cep + topk);
        atomicAdd(np_tot, sh_np);
        __threadfence();
        int d = atomicAdd(done_cnt, 1);
        if (d == NB - 1) {
            float sl = atomicAdd(sl_tot, 0.f);   // coherent reads incl. all contributions
            float cc = atomicAdd(c_tot, 0.f);
            int   np = atomicAdd(np_tot, 0);
            float N = fmaxf((float)np, 1.f);
            out[0] = sl / N;
            out[1] = cc / N;
        }
    }
}

extern "C" void kernel_launch(void* const* d_in, const int* in_sizes, int n_in,
                              void* d_out, int out_size, void* d_ws, size_t ws_size,
                              hipStream_t stream) {
    const float* loc     = (const float*)d_in[0];   // (B,P,4)
    const float* conf    = (const float*)d_in[1];   // (B,P,2)
    const float* priors  = (const float*)d_in[2];   // (P,4)
    const float* targets = (const float*)d_in[3];   // (B,O,5)
    float* out = (float*)d_out;

    char* ws = (char*)d_ws;
    float* mine     = (float*)ws;                       // 4 MB, fully written by K1
    u64*   bpk_part = (u64*)(ws + 4194304);             // 512 KB [b][64][32], fully written by K1
    float* part_sl1 = (float*)(ws + 4718592);           // [b][64] kern1 partials (8 KB each)
    float* part_cep = (float*)(ws + 4726784);
    int*   part_np  = (int*)(ws + 4734976);
    float* sl_tot   = (float*)(ws + 4743168);           // zero-inited by kern1 block (0,0)
    float* c_tot    = (float*)(ws + 4743172);
    int*   np_tot   = (int*)(ws + 4743176);
    int*   done_cnt = (int*)(ws + 4743180);

    dim3 g1(NT1, NB);
    kern1<<<g1, 256, 0, stream>>>(loc, conf, priors, targets, mine, bpk_part,
                                  part_sl1, part_cep, part_np,
                                  sl_tot, c_tot, np_tot, done_cnt);
    kern3<<<NB, 1024, 0, stream>>>(loc, conf, priors, targets, bpk_part, mine,
                                   part_sl1, part_cep, part_np,
                                   sl_tot, c_tot, np_tot, done_cnt, out);
}